// Round 5
// baseline (144.009 us; speedup 1.0000x reference)
//
#include <hip/hip_runtime.h>

// LRMU scan collapsed to out = U_rev^T @ P with P[j] = b·A^j via log-doubling.
// R5: single persistent kernel, fence-free barriers, and a write-once /
// first-touch coherence scheme: all cross-block data is written with sc1
// (write-around, lands at the coherence point) into buffers that are never
// read before their producing barrier within a dispatch, so NORMAL cached
// loads are safe for all reads (R4's sc1 loads bypassed L2 every time and
// were the 68us bottleneck). 8 distinct A-power buffers replace ping-pong.
// Dispatch-start L2 invalidate (proven by R4's cross-kernel replays) handles
// staleness across graph replays.

#define SEQ_T 256
#define DIM 128
#define ORD 256
#define BMROWS 2048

// float offsets into ws (write-once buffers, 2 KB guard gaps)
#define OFF_U 0                                  // U[t][bm]: 256*2048
#define OFF_P (OFF_U + SEQ_T * BMROWS)           // P[j][o]: 256*256
#define APSTRIDE (ORD * ORD + 2048)
#define OFF_AP (OFF_P + ORD * ORD + 2048)        // AP[j]=A^(2^j), j=1..7
#define OFF_FLAGS (OFF_AP + 7 * APSTRIDE + 2048) // 256 u32 barrier flags

#define LD_A(p) \
  __hip_atomic_load((p), __ATOMIC_RELAXED, __HIP_MEMORY_SCOPE_AGENT)
#define ST_A(p, v) \
  __hip_atomic_store((p), (v), __ATOMIC_RELAXED, __HIP_MEMORY_SCOPE_AGENT)

// Fence-free grid barrier over 256 blocks: each wave drains its own sc1
// stores (vmcnt 0), block barrier, then one thread stores the block's flag;
// thread tid polls flags[tid] so the block proceeds only when all 256
// blocks arrived. No __threadfence anywhere (no L2 writeback/invalidate).
__device__ __forceinline__ void gbar(unsigned* flags, unsigned target) {
  asm volatile("s_waitcnt vmcnt(0)" ::: "memory");
  __syncthreads();
  if ((int)threadIdx.x == (int)blockIdx.x) ST_A(&flags[threadIdx.x], target);
  while (LD_A(&flags[threadIdx.x]) < target) {
  }
  __syncthreads();
}

__global__ __launch_bounds__(256) void lrmu_all(
    const float* __restrict__ x, const float* __restrict__ K,
    const float* __restrict__ A, const float* __restrict__ Bm,
    float* __restrict__ out, float* __restrict__ ws) {
  __shared__ __align__(16) float Slds[ORD * 64];  // 64 KB: S col-slice / out red
  __shared__ __align__(16) float lsb[2048];       // 8 KB: chain left rows / out us
  __shared__ __align__(16) float redb[4 * 320];   // 5 KB: chain wave partials
  float* U = ws + OFF_U;
  float* P = ws + OFF_P;
  unsigned* flags = (unsigned*)(ws + OFF_FLAGS);
  const int blk = blockIdx.x, tid = threadIdx.x;

  // ---------- U phase: U[t][bm] = sum_d x[b][t][d] * K[d][m] ----------
  {
    int b = blk >> 4, tc = blk & 15;
    float* xs = Slds;
    for (int idx = tid; idx < 16 * DIM; idx += 256)
      xs[idx] = x[(b * SEQ_T + tc * 16) * DIM + idx];
    __syncthreads();
    int m = tid & 127, th = tid >> 7;
    float acc[8] = {};
#pragma unroll 8
    for (int d = 0; d < DIM; ++d) {
      float kv = K[d * DIM + m];  // coalesced, L2-resident after first touch
#pragma unroll
      for (int r = 0; r < 8; ++r)
        acc[r] = fmaf(xs[(th * 8 + r) * DIM + d], kv, acc[r]);
    }
#pragma unroll
    for (int r = 0; r < 8; ++r)  // sc1: read cross-XCD at out phase
      ST_A(&U[(tc * 16 + th * 8 + r) * BMROWS + b * DIM + m], acc[r]);
    if (blk == 0) ST_A(&P[tid], Bm[tid]);  // P[0][:] = b (first read: step 1)
    __syncthreads();  // before Slds reuse in chain
  }

  // ---------- chain: step k reads S=A^(2^k), writes S^2 and P doubling ----
  // block = (rg = blk>>2 in [0,64), cg = blk&3 64-col slice).
  // rows: 4 squaring rows (4rg..4rg+3; none at k=7) + doubling rows
  // (k<7: d=rg if rg<half; k=7: d=rg, rg+64).
  const int rg = blk >> 2, cg = blk & 3;
  const int lane = tid & 63, q = tid >> 6;
  const int ir = lane >> 4, c4 = (lane & 15) * 4;
  for (int k = 0; k < 8; ++k) {
    const float* S = (k == 0) ? A : (ws + OFF_AP + (k - 1) * APSTRIDE);
    float* Snew = ws + OFF_AP + ((k < 7) ? k : 6) * APSTRIDE;  // unused at k=7
    const int half = 1 << k;
    const int nsq = (k < 7) ? 4 : 0;
    const int ndb = (k == 7) ? 2 : (rg < half ? 1 : 0);
    const int nrows = nsq + ndb;

    // stage left rows (full 256 width) into lsb[5][256]; zero-pad unused
#pragma unroll
    for (int s = 0; s < 5; ++s) {
      float v = 0.f;
      if (s < nsq) {
        v = S[(4 * rg + s) * ORD + tid];
      } else if (s - nsq < ndb) {
        int d = rg + 64 * (s - nsq);
        v = (k == 0) ? Bm[tid] : P[d * ORD + tid];  // P rows write-once
      }
      lsb[s * ORD + tid] = v;
    }
    // stage right slice S[:, 64cg..+64) into Slds[256][64] via float4
#pragma unroll
    for (int j = 0; j < 16; ++j) {
      int f = tid + 256 * j;
      int i = f >> 4, cc = (f & 15) * 4;
      *(float4*)&Slds[i * 64 + cc] =
          *(const float4*)&S[i * ORD + cg * 64 + cc];
    }
    __syncthreads();

    // wave q covers K-chunk [64q,64q+64); lane = (ir K-subsplit, c4 cols)
    float acc[5][4] = {};
#pragma unroll 4
    for (int ii = 0; ii < 16; ++ii) {
      int i = q * 64 + 4 * ii + ir;
      float4 sv = *(const float4*)&Slds[i * 64 + c4];  // b128 LDS
#pragma unroll
      for (int s = 0; s < 5; ++s) {
        float lv = lsb[s * ORD + i];  // 4-address broadcast
        acc[s][0] = fmaf(lv, sv.x, acc[s][0]);
        acc[s][1] = fmaf(lv, sv.y, acc[s][1]);
        acc[s][2] = fmaf(lv, sv.z, acc[s][2]);
        acc[s][3] = fmaf(lv, sv.w, acc[s][3]);
      }
    }
    // reduce the ir split (lane bits 4-5) in-register
#pragma unroll
    for (int s = 0; s < 5; ++s)
#pragma unroll
      for (int w = 0; w < 4; ++w) {
        acc[s][w] += __shfl_xor(acc[s][w], 16);
        acc[s][w] += __shfl_xor(acc[s][w], 32);
      }
    if (ir == 0) {
#pragma unroll
      for (int s = 0; s < 5; ++s)
        *(float4*)&redb[q * 320 + s * 64 + c4] =
            make_float4(acc[s][0], acc[s][1], acc[s][2], acc[s][3]);
    }
    __syncthreads();
    // reduce the 4 wave partials, store via sc1 (write-once buffers)
    for (int o = tid; o < 320; o += 256) {
      int s = o >> 6, c = o & 63;
      if (s < nrows) {
        float sum = redb[o] + redb[320 + o] + redb[640 + o] + redb[960 + o];
        if (s < nsq) {
          ST_A(&Snew[(4 * rg + s) * ORD + cg * 64 + c], sum);
        } else {
          int d = rg + 64 * (s - nsq);
          ST_A(&P[(half + d) * ORD + cg * 64 + c], sum);
        }
      }
    }
    gbar(flags, (unsigned)(k + 1));
  }

  // ---------- out: out[bm][o] = sum_t U[t][bm] * P[255-t][o] ----------
  {
    float* us = lsb;    // [256][8]
    float* redo = Slds; // [4][8][256] wave partials
    int bm0 = blk * 8;
    for (int idx = tid; idx < SEQ_T * 8; idx += 256) {
      int t = idx >> 3, r = idx & 7;
      us[idx] = U[t * BMROWS + bm0 + r];  // normal load: first touch of U
    }
    __syncthreads();
    int c4o = lane * 4, qo = q;  // lane covers 4 cols; wave covers 64 t
    float ao[8][4] = {};
#pragma unroll 4
    for (int tt = 0; tt < 64; ++tt) {
      int t = qo * 64 + tt;
      float4 pv = *(const float4*)&P[(SEQ_T - 1 - t) * ORD + c4o];  // L2-hot
      float4 u0 = *(const float4*)&us[t * 8];      // LDS broadcast
      float4 u1 = *(const float4*)&us[t * 8 + 4];
      float uv[8] = {u0.x, u0.y, u0.z, u0.w, u1.x, u1.y, u1.z, u1.w};
      float pw[4] = {pv.x, pv.y, pv.z, pv.w};
#pragma unroll
      for (int r = 0; r < 8; ++r)
#pragma unroll
        for (int w = 0; w < 4; ++w)
          ao[r][w] = fmaf(uv[r], pw[w], ao[r][w]);
    }
#pragma unroll
    for (int r = 0; r < 8; ++r)
      *(float4*)&redo[qo * 2048 + r * 256 + c4o] =
          make_float4(ao[r][0], ao[r][1], ao[r][2], ao[r][3]);
    __syncthreads();
#pragma unroll
    for (int j = 0; j < 8; ++j) {
      int o = tid + 256 * j;  // o = r*256 + c
      float s = redo[o] + redo[2048 + o] + redo[4096 + o] + redo[6144 + o];
      out[bm0 * ORD + o] = s;  // normal store; kernel-end release flushes
    }
  }
}

extern "C" void kernel_launch(void* const* d_in, const int* in_sizes, int n_in,
                              void* d_out, int out_size, void* d_ws,
                              size_t ws_size, hipStream_t stream) {
  const float* x = (const float*)d_in[0];   // (16,256,128)
  const float* K = (const float*)d_in[1];   // (128,128)
  const float* A = (const float*)d_in[2];   // (256,256)
  const float* Bm = (const float*)d_in[3];  // (256,)
  float* out = (float*)d_out;               // (16, 32768)
  float* ws = (float*)d_ws;

  // zero barrier flags (ws re-poisoned 0xAA before every timed call)
  hipMemsetAsync(ws + OFF_FLAGS, 0, 256 * sizeof(unsigned), stream);
  lrmu_all<<<256, 256, 0, stream>>>(x, K, A, Bm, out, ws);
}

// Round 6
// 117.961 us; speedup vs baseline: 1.2208x; 1.2208x over previous
//
#include <hip/hip_runtime.h>

// LRMU scan collapsed to out = U_rev^T @ P with P[j] = b·A^j via log-doubling.
// R6 = R5's validated data scheme (sc1 write-once stores + normal cached
// loads; 8 distinct A-power buffers; single persistent kernel) with the
// barrier replaced by a 2-hop minimal-traffic design. R5 post-mortem: the
// ~9.4us/barrier cost was 65536 threads poll-hammering the coherence point
// with uncached loads (no s_sleep); R2/R3's cost was threadfence L2 flushes;
// R4's was sc1 data loads. R6 polls with 256 threads (block 0) + 255
// single-thread gen waiters, s_sleep(1) in loops.

#define SEQ_T 256
#define DIM 128
#define ORD 256
#define BMROWS 2048

// float offsets into ws (write-once buffers, guard gaps)
#define OFF_U 0                                  // U[t][bm]: 256*2048
#define OFF_P (OFF_U + SEQ_T * BMROWS)           // P[j][o]: 256*256
#define APSTRIDE (ORD * ORD + 2048)
#define OFF_AP (OFF_P + ORD * ORD + 2048)        // AP[j]=A^(2^(j+1))
#define OFF_FLAGS (OFF_AP + 7 * APSTRIDE + 2048) // 256 flags; gen at +320

#define LD_A(p) \
  __hip_atomic_load((p), __ATOMIC_RELAXED, __HIP_MEMORY_SCOPE_AGENT)
#define ST_A(p, v) \
  __hip_atomic_store((p), (v), __ATOMIC_RELAXED, __HIP_MEMORY_SCOPE_AGENT)

// 2-hop fence-free grid barrier (256 blocks). No __threadfence anywhere;
// correctness comes from sc1 write-once buffers + vmcnt drain before arrival.
__device__ __forceinline__ void gbar(unsigned* flags, unsigned* gen,
                                     unsigned target) {
  asm volatile("s_waitcnt vmcnt(0)" ::: "memory");  // drain this wave's sc1 st
  __syncthreads();  // now ALL waves of the block have drained
  const int tid = threadIdx.x;
  if (blockIdx.x == 0) {
    if (tid == 0) ST_A(&flags[0], target);
    while (LD_A(&flags[tid]) < target) __builtin_amdgcn_s_sleep(1);
    __syncthreads();  // all 256 flags seen
    if (tid == 0) ST_A(gen, target);
  } else {
    if (tid == 0) {
      ST_A(&flags[blockIdx.x], target);
      while (LD_A(gen) < target) __builtin_amdgcn_s_sleep(1);
    }
  }
  __syncthreads();
}

__global__ __launch_bounds__(256) void lrmu_all(
    const float* __restrict__ x, const float* __restrict__ K,
    const float* __restrict__ A, const float* __restrict__ Bm,
    float* __restrict__ out, float* __restrict__ ws) {
  __shared__ __align__(16) float Slds[ORD * 64];  // 64 KB: S col-slice / out red
  __shared__ __align__(16) float lsb[2048];       // 8 KB: chain left rows / us
  __shared__ __align__(16) float redb[4 * 320];   // 5 KB: chain wave partials
  float* U = ws + OFF_U;
  float* P = ws + OFF_P;
  unsigned* flags = (unsigned*)(ws + OFF_FLAGS);
  unsigned* gen = flags + 320;
  const int blk = blockIdx.x, tid = threadIdx.x;

  // ---------- U phase: U[t][bm] = sum_d x[b][t][d] * K[d][m] ----------
  {
    int b = blk >> 4, tc = blk & 15;
    float* xs = Slds;
    for (int idx = tid; idx < 16 * DIM; idx += 256)
      xs[idx] = x[(b * SEQ_T + tc * 16) * DIM + idx];
    __syncthreads();
    int m = tid & 127, th = tid >> 7;
    float acc[8] = {};
#pragma unroll 8
    for (int d = 0; d < DIM; ++d) {
      float kv = K[d * DIM + m];  // coalesced, L2-resident
#pragma unroll
      for (int r = 0; r < 8; ++r)
        acc[r] = fmaf(xs[(th * 8 + r) * DIM + d], kv, acc[r]);
    }
#pragma unroll
    for (int r = 0; r < 8; ++r)  // sc1: read cross-XCD at out phase
      ST_A(&U[(tc * 16 + th * 8 + r) * BMROWS + b * DIM + m], acc[r]);
    if (blk == 0) ST_A(&P[tid], Bm[tid]);  // P[0][:] = b
    __syncthreads();  // before Slds reuse in chain
  }

  // ---------- chain: step k reads S=A^(2^k), writes S^2 and P doubling ----
  const int rg = blk >> 2, cg = blk & 3;
  const int lane = tid & 63, q = tid >> 6;
  const int ir = lane >> 4, c4 = (lane & 15) * 4;
  for (int k = 0; k < 8; ++k) {
    const float* S = (k == 0) ? A : (ws + OFF_AP + (k - 1) * APSTRIDE);
    float* Snew = ws + OFF_AP + ((k < 7) ? k : 6) * APSTRIDE;  // unused k=7
    const int half = 1 << k;
    const int nsq = (k < 7) ? 4 : 0;
    const int ndb = (k == 7) ? 2 : (rg < half ? 1 : 0);
    const int nrows = nsq + ndb;

    // stage left rows into lsb[5][256]; zero-pad unused
#pragma unroll
    for (int s = 0; s < 5; ++s) {
      float v = 0.f;
      if (s < nsq) {
        v = S[(4 * rg + s) * ORD + tid];
      } else if (s - nsq < ndb) {
        int d = rg + 64 * (s - nsq);
        v = (k == 0) ? Bm[tid] : P[d * ORD + tid];  // write-once P rows
      }
      lsb[s * ORD + tid] = v;
    }
    // stage right slice S[:, 64cg..+64) into Slds[256][64] via float4
#pragma unroll
    for (int j = 0; j < 16; ++j) {
      int f = tid + 256 * j;
      int i = f >> 4, cc = (f & 15) * 4;
      *(float4*)&Slds[i * 64 + cc] =
          *(const float4*)&S[i * ORD + cg * 64 + cc];
    }
    __syncthreads();

    // wave q covers K-chunk [64q,64q+64); lane = (ir K-subsplit, c4 cols)
    float acc[5][4] = {};
#pragma unroll 4
    for (int ii = 0; ii < 16; ++ii) {
      int i = q * 64 + 4 * ii + ir;
      float4 sv = *(const float4*)&Slds[i * 64 + c4];  // b128 LDS
#pragma unroll
      for (int s = 0; s < 5; ++s) {
        float lv = lsb[s * ORD + i];  // broadcast
        acc[s][0] = fmaf(lv, sv.x, acc[s][0]);
        acc[s][1] = fmaf(lv, sv.y, acc[s][1]);
        acc[s][2] = fmaf(lv, sv.z, acc[s][2]);
        acc[s][3] = fmaf(lv, sv.w, acc[s][3]);
      }
    }
#pragma unroll
    for (int s = 0; s < 5; ++s)
#pragma unroll
      for (int w = 0; w < 4; ++w) {
        acc[s][w] += __shfl_xor(acc[s][w], 16);
        acc[s][w] += __shfl_xor(acc[s][w], 32);
      }
    if (ir == 0) {
#pragma unroll
      for (int s = 0; s < 5; ++s)
        *(float4*)&redb[q * 320 + s * 64 + c4] =
            make_float4(acc[s][0], acc[s][1], acc[s][2], acc[s][3]);
    }
    __syncthreads();
    for (int o = tid; o < 320; o += 256) {
      int s = o >> 6, c = o & 63;
      if (s < nrows) {
        float sum = redb[o] + redb[320 + o] + redb[640 + o] + redb[960 + o];
        if (s < nsq) {
          ST_A(&Snew[(4 * rg + s) * ORD + cg * 64 + c], sum);
        } else {
          int d = rg + 64 * (s - nsq);
          ST_A(&P[(half + d) * ORD + cg * 64 + c], sum);
        }
      }
    }
    gbar(flags, gen, (unsigned)(k + 1));
  }

  // ---------- out: out[bm][o] = sum_t U[t][bm] * P[255-t][o] ----------
  {
    float* us = lsb;     // [256][8]
    float* redo = Slds;  // [4][8][256] wave partials
    int bm0 = blk * 8;
    for (int idx = tid; idx < SEQ_T * 8; idx += 256) {
      int t = idx >> 3, r = idx & 7;
      us[idx] = U[t * BMROWS + bm0 + r];  // normal load: first touch of U
    }
    __syncthreads();
    int c4o = lane * 4, qo = q;  // lane: 4 cols; wave: 64 t's
    float ao[8][4] = {};
#pragma unroll 4
    for (int tt = 0; tt < 64; ++tt) {
      int t = qo * 64 + tt;
      float4 pv = *(const float4*)&P[(SEQ_T - 1 - t) * ORD + c4o];  // L2-hot
      float4 u0 = *(const float4*)&us[t * 8];  // LDS broadcast
      float4 u1 = *(const float4*)&us[t * 8 + 4];
      float uv[8] = {u0.x, u0.y, u0.z, u0.w, u1.x, u1.y, u1.z, u1.w};
      float pw[4] = {pv.x, pv.y, pv.z, pv.w};
#pragma unroll
      for (int r = 0; r < 8; ++r)
#pragma unroll
        for (int w = 0; w < 4; ++w)
          ao[r][w] = fmaf(uv[r], pw[w], ao[r][w]);
    }
#pragma unroll
    for (int r = 0; r < 8; ++r)
      *(float4*)&redo[qo * 2048 + r * 256 + c4o] =
          make_float4(ao[r][0], ao[r][1], ao[r][2], ao[r][3]);
    __syncthreads();
#pragma unroll
    for (int j = 0; j < 8; ++j) {
      int o = tid + 256 * j;  // o = r*256 + c
      float s = redo[o] + redo[2048 + o] + redo[4096 + o] + redo[6144 + o];
      out[bm0 * ORD + o] = s;  // kernel-end release flushes
    }
  }
}

extern "C" void kernel_launch(void* const* d_in, const int* in_sizes, int n_in,
                              void* d_out, int out_size, void* d_ws,
                              size_t ws_size, hipStream_t stream) {
  const float* x = (const float*)d_in[0];   // (16,256,128)
  const float* K = (const float*)d_in[1];   // (128,128)
  const float* A = (const float*)d_in[2];   // (256,256)
  const float* Bm = (const float*)d_in[3];  // (256,)
  float* out = (float*)d_out;               // (16, 32768)
  float* ws = (float*)d_ws;

  // zero barrier flags + gen (ws re-poisoned 0xAA before every timed call)
  hipMemsetAsync(ws + OFF_FLAGS, 0, 2048, stream);
  lrmu_all<<<256, 256, 0, stream>>>(x, K, A, Bm, out, ws);
}